// Round 4
// baseline (135.514 us; speedup 1.0000x reference)
//
#include <hip/hip_runtime.h>
#include <stdint.h>

#define S 2048
#define DHEAD 64
#define CDIM 256
#define NBATCH 8

typedef __attribute__((ext_vector_type(4))) float f32x4;
typedef __attribute__((ext_vector_type(8))) short s16x8;
typedef __attribute__((ext_vector_type(8))) _Float16 f16x8;
typedef __attribute__((ext_vector_type(4))) unsigned short u16x4;

static __device__ __forceinline__ unsigned short f2bf(float f) {
    unsigned int u = __builtin_bit_cast(unsigned int, f);
    unsigned int r = (u + 0x7FFFu + ((u >> 16) & 1u)) >> 16;  // RNE
    return (unsigned short)r;
}
static __device__ __forceinline__ unsigned short f2h(float f) {
    _Float16 h = (_Float16)f;
    return __builtin_bit_cast(unsigned short, h);
}

// ---------------- kernel 0: a (fp32) -> a16 (bf16) ----------------
__global__ __launch_bounds__(256) void cvt_a_kernel(const float* __restrict__ a,
                                                    unsigned short* __restrict__ a16,
                                                    int n4) {
    int i = blockIdx.x * 256 + threadIdx.x;
    int stride = gridDim.x * 256;
    for (; i < n4; i += stride) {
        f32x4 v = ((const f32x4*)a)[i];
        u16x4 o;
        o.x = f2bf(v.x); o.y = f2bf(v.y); o.z = f2bf(v.z); o.w = f2bf(v.w);
        ((u16x4*)a16)[i] = o;
    }
}

// ---------------- fused kernel ----------------
// Block (512 thr, 8 waves) owns 32 out-columns (n) x all 256 c-rows, 1 batch.
// Grid 512 = 64 n-tiles x 8 batches -> 2 blocks/CU. Loop 16 m-tiles (128 m):
//   scores: s[128m][32n] = c-tile(f16) x b-tile(f16) MFMA (R2-verified layout)
//   E = exp(s) -> bf16 LDS es[32n][128m+pad]; row-sums L in regs
//   PV: acc[256c][32n] += a16[c][m-tile] (L2) x es^T  (R3-verified layout)
// T14: next c-tile global loads issued right after B2 (hide under PV).
__global__ __launch_bounds__(512, 4) void fused_kernel(
    const float* __restrict__ Bq, const float* __restrict__ Ck,
    const unsigned short* __restrict__ a16, const float* __restrict__ afull,
    float* __restrict__ out)
{
    // XCD-chunked bijective swizzle: 512 blocks round-robin XCDs by default;
    // remap so batch gb = XCD, 64 n-tiles of it contiguous on that XCD.
    const int bid = blockIdx.x;
    const int xcd = bid & 7;
    const int gb = xcd;
    const int nt = bid >> 3;          // 0..63
    const int n0 = nt * 32;

    const float* __restrict__ bp = Bq + (size_t)gb * S * DHEAD;
    const float* __restrict__ cp = Ck + (size_t)gb * S * DHEAD;
    const unsigned short* __restrict__ ap16 = a16 + (size_t)gb * CDIM * S;
    const float* __restrict__ ap = afull + (size_t)gb * CDIM * S;
    float* __restrict__ op = out + (size_t)gb * CDIM * S;

    __shared__ unsigned short bs[32 * 72];    // f16 b rows (n), pad 72
    __shared__ unsigned short cs[128 * 72];   // f16 c rows (m), pad 72
    __shared__ unsigned short es[32 * 136];   // bf16 E [n][m], pad 136
    __shared__ float Lsh[8 * 16];

    const int tid = threadIdx.x;
    const int lane = tid & 63;
    const int w = tid >> 6;
    const int q = lane >> 4, r15 = lane & 15;
    const int sn = w & 1, sm = w >> 1;        // scores: n 16-group, m 32-group
    const int wrc = w >> 1, wn = w & 1;       // PV: c 64-group, n 16-group

    // prologue: stage b-tile (32 rows) once, fp32 -> f16
    {
        int row = tid >> 4, c4 = tid & 15;
        if (row < 32) {
            f32x4 v = *(const f32x4*)&bp[(size_t)(n0 + row) * DHEAD + c4 * 4];
            u16x4 o;
            o.x = f2h(v.x); o.y = f2h(v.y); o.z = f2h(v.z); o.w = f2h(v.w);
            *(u16x4*)&bs[row * 72 + c4 * 4] = o;
        }
    }
    // prologue: load c-tile 0 into regs
    f32x4 cv[4];
    #pragma unroll
    for (int t = 0; t < 4; ++t) {
        int ch = tid + 512 * t;
        int row = ch >> 4, c4 = ch & 15;
        cv[t] = *(const f32x4*)&cp[(size_t)row * DHEAD + c4 * 4];
    }

    f32x4 acc[4] = {};
    float Lrun = 0.f;

    for (int mt = 0; mt < 16; ++mt) {
        const int m0 = mt * 128;

        // write staged c-tile regs -> cs (cs free: all waves past prev B2)
        #pragma unroll
        for (int t = 0; t < 4; ++t) {
            int ch = tid + 512 * t;
            int row = ch >> 4, c4 = ch & 15;
            u16x4 o;
            o.x = f2h(cv[t].x); o.y = f2h(cv[t].y);
            o.z = f2h(cv[t].z); o.w = f2h(cv[t].w);
            *(u16x4*)&cs[row * 72 + c4 * 4] = o;
        }
        __syncthreads();  // B1: cs/bs visible; prev PV es-reads retired

        // scores: wave (sn, sm): frags m = sm*32 + i*16, n-group sn. K=64.
        f32x4 sacc[2] = {};
        #pragma unroll
        for (int kk = 0; kk < 2; ++kk) {
            f16x8 bfr = *(const f16x8*)&bs[(sn * 16 + r15) * 72 + kk * 32 + q * 8];
            #pragma unroll
            for (int i = 0; i < 2; ++i) {
                f16x8 afr = *(const f16x8*)&cs[(sm * 32 + i * 16 + r15) * 72 + kk * 32 + q * 8];
                sacc[i] = __builtin_amdgcn_mfma_f32_16x16x32_f16(afr, bfr, sacc[i], 0, 0, 0);
            }
        }

        // exp + pack + es write [n][m]; accumulate row sums
        #pragma unroll
        for (int i = 0; i < 2; ++i) {
            float e0 = __expf(sacc[i][0]);
            float e1 = __expf(sacc[i][1]);
            float e2 = __expf(sacc[i][2]);
            float e3 = __expf(sacc[i][3]);
            Lrun += (e0 + e1) + (e2 + e3);
            u16x4 pk;
            pk.x = f2bf(e0); pk.y = f2bf(e1); pk.z = f2bf(e2); pk.w = f2bf(e3);
            *(u16x4*)&es[(sn * 16 + r15) * 136 + sm * 32 + i * 16 + q * 4] = pk;
        }

        // prefetch PV A-frags ks=0 (L2), consumed after B2
        s16x8 afc[4];
        #pragma unroll
        for (int i = 0; i < 4; ++i)
            afc[i] = *(const s16x8*)&ap16[(size_t)(wrc * 64 + i * 16 + r15) * S + m0 + q * 8];

        __syncthreads();  // B2: es visible

        // T14: issue next c-tile global loads now; latency hides under PV
        if (mt < 15) {
            #pragma unroll
            for (int t = 0; t < 4; ++t) {
                int ch = tid + 512 * t;
                int row = ch >> 4, c4 = ch & 15;
                cv[t] = *(const f32x4*)&cp[(size_t)(m0 + 128 + row) * DHEAD + c4 * 4];
            }
        }

        // PV: acc[c 64-group][n 16-group] += a16 x es^T, K=128 (4 ks)
        #pragma unroll
        for (int ks = 0; ks < 4; ++ks) {
            s16x8 afn[4];
            if (ks < 3) {
                #pragma unroll
                for (int i = 0; i < 4; ++i)
                    afn[i] = *(const s16x8*)&ap16[(size_t)(wrc * 64 + i * 16 + r15) * S + m0 + (ks + 1) * 32 + q * 8];
            }
            s16x8 bfr = *(const s16x8*)&es[(wn * 16 + r15) * 136 + ks * 32 + q * 8];
            #pragma unroll
            for (int i = 0; i < 4; ++i)
                acc[i] = __builtin_amdgcn_mfma_f32_16x16x32_bf16(afc[i], bfr, acc[i], 0, 0, 0);
            #pragma unroll
            for (int i = 0; i < 4; ++i) afc[i] = afn[i];
        }
    }

    // reduce L over q groups, then over sm waves via LDS
    Lrun += __shfl_xor(Lrun, 16);
    Lrun += __shfl_xor(Lrun, 32);
    if (lane < 16) Lsh[w * 16 + lane] = Lrun;
    __syncthreads();

    // epilogue: out = acc / L + a.  n = wn*16 + r15
    float Lv = 0.f;
    #pragma unroll
    for (int smi = 0; smi < 4; ++smi)
        Lv += Lsh[(smi * 2 + wn) * 16 + r15];
    const float rcpL = 1.0f / Lv;

    #pragma unroll
    for (int i = 0; i < 4; ++i) {
        #pragma unroll
        for (int rr = 0; rr < 4; ++rr) {
            int cc = wrc * 64 + i * 16 + q * 4 + rr;
            size_t base = (size_t)cc * S + n0;
            int nloc = wn * 16 + r15;
            op[base + nloc] = acc[i][rr] * rcpL + ap[base + nloc];
        }
    }
}

// ---------------- launch ----------------
extern "C" void kernel_launch(void* const* d_in, const int* in_sizes, int n_in,
                              void* d_out, int out_size, void* d_ws, size_t ws_size,
                              hipStream_t stream) {
    const float* a = (const float*)d_in[0];
    const float* b = (const float*)d_in[1];
    const float* c = (const float*)d_in[2];
    float* out = (float*)d_out;

    unsigned short* a16 = (unsigned short*)d_ws;  // 8 MB

    cvt_a_kernel<<<1024, 256, 0, stream>>>(a, a16, NBATCH * CDIM * S / 4);
    fused_kernel<<<512, 512, 0, stream>>>(b, c, a16, a, out);
}

// Round 6
// 62.918 us; speedup vs baseline: 2.1538x; 2.1538x over previous
//
#include <hip/hip_runtime.h>
#include <stdint.h>

#define S 2048
#define DHEAD 64
#define CDIM 256
#define NBATCH 8
#define NMT 16  // S/128 m-tiles

typedef __attribute__((ext_vector_type(4))) float f32x4;
typedef __attribute__((ext_vector_type(8))) short s16x8;
typedef __attribute__((ext_vector_type(8))) _Float16 f16x8;
typedef __attribute__((ext_vector_type(4))) unsigned short u16x4;

static __device__ __forceinline__ unsigned short f2bf(float f) {
    unsigned int u = __builtin_bit_cast(unsigned int, f);
    unsigned int r = (u + 0x7FFFu + ((u >> 16) & 1u)) >> 16;  // RNE
    return (unsigned short)r;
}
static __device__ __forceinline__ unsigned short f2h(float f) {
    _Float16 h = (_Float16)f;
    return __builtin_bit_cast(unsigned short, h);
}

// ---------------- kernel 0: a (fp32) -> a16 (bf16) ----------------
__global__ __launch_bounds__(256) void cvt_a_kernel(const float* __restrict__ a,
                                                    unsigned short* __restrict__ a16,
                                                    int n4) {
    int i = blockIdx.x * 256 + threadIdx.x;
    int stride = gridDim.x * 256;
    for (; i < n4; i += stride) {
        f32x4 v = ((const f32x4*)a)[i];
        u16x4 o;
        o.x = f2bf(v.x); o.y = f2bf(v.y); o.z = f2bf(v.z); o.w = f2bf(v.w);
        ((u16x4*)a16)[i] = o;
    }
}

// ---------------- kernel 1: E = exp(b @ c^T) via f16 MFMA (R2-verified) ----
// 1-D grid; when nb==8, batch==XCD so E lines land in that XCD's L2.
__global__ __launch_bounds__(256) void scores_kernel(
    const float* __restrict__ Bq, const float* __restrict__ Ck,
    unsigned short* __restrict__ E, float* __restrict__ Lp, int b0, int nb)
{
    const int bid = blockIdx.x;
    int lb, idx;
    if (nb == 8) { lb = bid & 7; idx = bid >> 3; }
    else { lb = bid / (NMT * 16); idx = bid - lb * (NMT * 16); }
    const int gb = b0 + lb;
    const int mt = idx & 15;
    const int m0 = mt * 128;
    const int n0 = (idx >> 4) * 128;
    const float* __restrict__ bp = Bq + (size_t)gb * S * DHEAD;
    const float* __restrict__ cp = Ck + (size_t)gb * S * DHEAD;
    unsigned short* __restrict__ Ep = E + (size_t)lb * S * S;

    extern __shared__ char smem[];
    unsigned short* cs = (unsigned short*)smem;        // [128][72] f16 (m rows)
    unsigned short* bs = cs + 128 * 72;                // [128][72] f16 (n rows)
    unsigned short* es = (unsigned short*)smem;        // [128][136] bf16, ALIASES cs/bs
    float* Lsh = (float*)(smem + 2 * 128 * 72 * 2);    // [2][128]

    const int tid = threadIdx.x;
    const int lane = tid & 63;
    const int wid = tid >> 6;
    const int wr = wid >> 1, wc = wid & 1;
    const int q = lane >> 4, r15 = lane & 15;

    #pragma unroll
    for (int t = 0; t < 8; ++t) {
        int ch = tid + 256 * t;
        int row = ch >> 4, c4 = ch & 15;
        f32x4 cv = *(const f32x4*)&cp[(size_t)(m0 + row) * DHEAD + c4 * 4];
        f32x4 bv = *(const f32x4*)&bp[(size_t)(n0 + row) * DHEAD + c4 * 4];
        u16x4 co, bo;
        co.x = f2h(cv.x); co.y = f2h(cv.y); co.z = f2h(cv.z); co.w = f2h(cv.w);
        bo.x = f2h(bv.x); bo.y = f2h(bv.y); bo.z = f2h(bv.z); bo.w = f2h(bv.w);
        *(u16x4*)&cs[row * 72 + c4 * 4] = co;
        *(u16x4*)&bs[row * 72 + c4 * 4] = bo;
    }
    __syncthreads();

    f32x4 acc[4][4] = {};
    #pragma unroll
    for (int kk = 0; kk < 2; ++kk) {
        f16x8 af[4], bf[4];
        #pragma unroll
        for (int i = 0; i < 4; ++i)
            af[i] = *(const f16x8*)&cs[(wr * 64 + i * 16 + r15) * 72 + kk * 32 + q * 8];
        #pragma unroll
        for (int j = 0; j < 4; ++j)
            bf[j] = *(const f16x8*)&bs[(wc * 64 + j * 16 + r15) * 72 + kk * 32 + q * 8];
        #pragma unroll
        for (int i = 0; i < 4; ++i)
            #pragma unroll
            for (int j = 0; j < 4; ++j)
                acc[i][j] = __builtin_amdgcn_mfma_f32_16x16x32_f16(af[i], bf[j], acc[i][j], 0, 0, 0);
    }

    u16x4 pk[4][4];
    float sj[4] = {0.f, 0.f, 0.f, 0.f};
    #pragma unroll
    for (int i = 0; i < 4; ++i) {
        #pragma unroll
        for (int j = 0; j < 4; ++j) {
            float e0 = __expf(acc[i][j][0]);
            float e1 = __expf(acc[i][j][1]);
            float e2 = __expf(acc[i][j][2]);
            float e3 = __expf(acc[i][j][3]);
            pk[i][j].x = f2bf(e0); pk[i][j].y = f2bf(e1);
            pk[i][j].z = f2bf(e2); pk[i][j].w = f2bf(e3);
            sj[j] += (e0 + e1) + (e2 + e3);
        }
    }
    #pragma unroll
    for (int j = 0; j < 4; ++j) {
        sj[j] += __shfl_xor(sj[j], 16);
        sj[j] += __shfl_xor(sj[j], 32);
    }

    __syncthreads();

    #pragma unroll
    for (int i = 0; i < 4; ++i)
        #pragma unroll
        for (int j = 0; j < 4; ++j) {
            int nl = wc * 64 + j * 16 + r15;
            int ml = wr * 64 + i * 16 + q * 4;
            *(u16x4*)&es[nl * 136 + ml] = pk[i][j];
        }
    if (q == 0) {
        #pragma unroll
        for (int j = 0; j < 4; ++j)
            Lsh[wr * 128 + wc * 64 + j * 16 + r15] = sj[j];
    }
    __syncthreads();

    if (tid < 128)
        Lp[(size_t)lb * NMT * S + (size_t)mt * S + n0 + tid] = Lsh[tid] + Lsh[128 + tid];

    #pragma unroll
    for (int t = 0; t < 8; ++t) {
        int ch = tid + 256 * t;
        int row = ch >> 4, off = ch & 15;
        f32x4 v = *(const f32x4*)&es[row * 136 + off * 8];
        *(f32x4*)&Ep[(size_t)(n0 + row) * S + m0 + off * 8] = v;
    }
}

// ---------------- kernel 2: out = (a16 @ E^T) / L + a ----------------
// 128c x 64n tile, BK=64, 4 waves (2 wr x 2 wc), T14 reg-prefetch.
// Grid 64*nb blocks (2 ct x 32 nt per batch); nb==8 -> batch==XCD.
__global__ __launch_bounds__(256, 4) void gemm_kernel(
    const unsigned short* __restrict__ a16, const unsigned short* __restrict__ E,
    const float* __restrict__ Lp, const float* __restrict__ afull,
    float* __restrict__ out, int b0, int nb)
{
    const int bid = blockIdx.x;
    int lb, idx;
    if (nb == 8) { lb = bid & 7; idx = bid >> 3; }
    else { lb = bid / 64; idx = bid - lb * 64; }
    const int gb = b0 + lb;
    const int nt = idx >> 1, ct = idx & 1;   // nt 0..31, ct-pairs adjacent -> share E rows in L2
    const int n0 = nt * 64, c0 = ct * 128;

    const unsigned short* __restrict__ Ap = a16 + (size_t)gb * CDIM * S;
    const unsigned short* __restrict__ Bp = E + (size_t)lb * S * S;
    const float* __restrict__ ap = afull + (size_t)gb * CDIM * S;
    float* __restrict__ op = out + (size_t)gb * CDIM * S;

    __shared__ unsigned short As[128 * 72];  // rows padded to 72 shorts (144 B)
    __shared__ unsigned short Bs[64 * 72];

    const int tid = threadIdx.x;
    const int lane = tid & 63;
    const int w = tid >> 6;
    const int wr = w >> 1, wc = w & 1;
    const int q = lane >> 4, r15 = lane & 15;

    // staging chunk decode (16 B chunks; 8 chunks per 64-short row)
    const int arow[4] = { (tid) >> 3, (tid + 256) >> 3, (tid + 512) >> 3, (tid + 768) >> 3 };
    const int aoff[4] = { (tid) & 7, (tid + 256) & 7, (tid + 512) & 7, (tid + 768) & 7 };
    const int brow[2] = { (tid) >> 3, (tid + 256) >> 3 };
    const int boff[2] = { (tid) & 7, (tid + 256) & 7 };

    f32x4 acc[4][2] = {};
    f32x4 avr[4], bvr[2];

    // prologue: load K-tile 0
    #pragma unroll
    for (int t = 0; t < 4; ++t)
        avr[t] = *(const f32x4*)&Ap[(size_t)(c0 + arow[t]) * S + aoff[t] * 8];
    #pragma unroll
    for (int t = 0; t < 2; ++t)
        bvr[t] = *(const f32x4*)&Bp[(size_t)(n0 + brow[t]) * S + boff[t] * 8];

    #pragma unroll 2
    for (int kt = 0; kt < S / 64; ++kt) {
        __syncthreads();  // prev MFMA ds_reads retired
        #pragma unroll
        for (int t = 0; t < 4; ++t)
            *(f32x4*)&As[arow[t] * 72 + aoff[t] * 8] = avr[t];
        #pragma unroll
        for (int t = 0; t < 2; ++t)
            *(f32x4*)&Bs[brow[t] * 72 + boff[t] * 8] = bvr[t];
        __syncthreads();  // staged

        // T14: issue next K-tile loads; latency hides under MFMA below
        if (kt < S / 64 - 1) {
            const int k0n = (kt + 1) * 64;
            #pragma unroll
            for (int t = 0; t < 4; ++t)
                avr[t] = *(const f32x4*)&Ap[(size_t)(c0 + arow[t]) * S + k0n + aoff[t] * 8];
            #pragma unroll
            for (int t = 0; t < 2; ++t)
                bvr[t] = *(const f32x4*)&Bp[(size_t)(n0 + brow[t]) * S + k0n + boff[t] * 8];
        }

        #pragma unroll
        for (int kk = 0; kk < 2; ++kk) {
            s16x8 af[4], bf[2];
            #pragma unroll
            for (int i = 0; i < 4; ++i)
                af[i] = *(const s16x8*)&As[(wr * 64 + i * 16 + r15) * 72 + kk * 32 + q * 8];
            #pragma unroll
            for (int j = 0; j < 2; ++j)
                bf[j] = *(const s16x8*)&Bs[(wc * 32 + j * 16 + r15) * 72 + kk * 32 + q * 8];
            #pragma unroll
            for (int i = 0; i < 4; ++i)
                #pragma unroll
                for (int j = 0; j < 2; ++j)
                    acc[i][j] = __builtin_amdgcn_mfma_f32_16x16x32_bf16(af[i], bf[j], acc[i][j], 0, 0, 0);
        }
    }

    // epilogue: out = acc / L[n] + a  (L = sum of 16 per-m-tile partials)
    float rcpL[2];
    #pragma unroll
    for (int j = 0; j < 2; ++j) {
        int n = n0 + wc * 32 + j * 16 + r15;
        float s = 0.f;
        #pragma unroll
        for (int mt = 0; mt < NMT; ++mt)
            s += Lp[(size_t)lb * NMT * S + (size_t)mt * S + n];
        rcpL[j] = 1.0f / s;
    }
    #pragma unroll
    for (int i = 0; i < 4; ++i) {
        #pragma unroll
        for (int rr = 0; rr < 4; ++rr) {
            int cc = c0 + wr * 64 + i * 16 + q * 4 + rr;
            size_t base = (size_t)cc * S;
            #pragma unroll
            for (int j = 0; j < 2; ++j) {
                int n = n0 + wc * 32 + j * 16 + r15;
                op[base + n] = acc[i][j][rr] * rcpL[j] + ap[base + n];
            }
        }
    }
}

// ---------------- launch ----------------
extern "C" void kernel_launch(void* const* d_in, const int* in_sizes, int n_in,
                              void* d_out, int out_size, void* d_ws, size_t ws_size,
                              hipStream_t stream) {
    const float* a = (const float*)d_in[0];
    const float* b = (const float*)d_in[1];
    const float* c = (const float*)d_in[2];
    float* out = (float*)d_out;

    const size_t a16_bytes = (size_t)NBATCH * CDIM * S * 2;              // 8 MB
    const size_t perb = (size_t)S * S * 2 + (size_t)NMT * S * 4;         // ~8.5 MB per batch
    int G = 1;
    if (ws_size > a16_bytes + perb) {
        size_t g = (ws_size - a16_bytes) / perb;
        G = (g >= NBATCH) ? NBATCH : (int)g;
        if (G < 1) G = 1;
    }
    unsigned short* a16 = (unsigned short*)d_ws;
    unsigned short* E = (unsigned short*)((char*)d_ws + a16_bytes);
    float* Lp = (float*)((char*)d_ws + a16_bytes + (size_t)G * S * S * 2);

    cvt_a_kernel<<<1024, 256, 0, stream>>>(a, a16, NBATCH * CDIM * S / 4);

    const size_t lds1 = 2 * 128 * 72 * 2 + 2 * 128 * 4;   // 37888 B
    for (int b0 = 0; b0 < NBATCH; b0 += G) {
        int nb = (NBATCH - b0 < G) ? (NBATCH - b0) : G;
        scores_kernel<<<NMT * 16 * nb, 256, lds1, stream>>>(b, c, E, Lp, b0, nb);
        gemm_kernel<<<64 * nb, 256, 0, stream>>>(a16, E, Lp, a, out, b0, nb);
    }
}